// Round 2
// baseline (595.398 us; speedup 1.0000x reference)
//
#include <hip/hip_runtime.h>
#include <hip/hip_bf16.h>

#define NN 50000
#define EE 800000
#define DD 128

typedef __attribute__((ext_vector_type(8))) short bf16x8;
typedef __attribute__((ext_vector_type(4))) float f32x4;

__device__ __forceinline__ short f2bf(float f) {
    __hip_bfloat16 h = __float2bfloat16(f);
    return __builtin_bit_cast(short, h);
}

__device__ __forceinline__ float bf2f(short s) {
    unsigned int u = ((unsigned int)(unsigned short)s) << 16;
    return __builtin_bit_cast(float, u);
}

__device__ __forceinline__ float fast_silu(float x) {
    return x / (1.0f + __expf(-x));
}

// ---- prep: h (fp32) -> bf16, zero agg (fp32), zero hist counters ----
__global__ void prep_kernel(const float* __restrict__ h, unsigned short* __restrict__ hp,
                            float4* __restrict__ agg4, int* __restrict__ cnt) {
    int t = blockIdx.x * blockDim.x + threadIdx.x;   // 1.6M threads exactly
    float4 v = ((const float4*)h)[t];
    ushort4 o;
    o.x = (unsigned short)f2bf(v.x);
    o.y = (unsigned short)f2bf(v.y);
    o.z = (unsigned short)f2bf(v.z);
    o.w = (unsigned short)f2bf(v.w);
    ((ushort4*)hp)[t] = o;
    agg4[t] = make_float4(0.f, 0.f, 0.f, 0.f);       // 6.4M floats = 1.6M float4 exactly
    if (t < NN) cnt[t] = 0;
}

// ---- counting sort, phase 1: histogram of receivers ----
__global__ void hist_kernel(const int* __restrict__ ei, int* __restrict__ cnt) {
    int e = blockIdx.x * 256 + threadIdx.x;
    atomicAdd(&cnt[ei[EE + e]], 1);
}

// ---- counting sort, phase 2: exclusive scan (1 block, 1024 threads) ----
__global__ void scan_kernel(const int* __restrict__ cnt, int* __restrict__ off,
                            int* __restrict__ cursor) {
    __shared__ int part[1024];
    const int t = threadIdx.x;
    const int CH = 49;                               // 1024*49 = 50176 >= NN
    int lo = t * CH, hi = lo + CH;
    if (hi > NN) hi = NN;
    int s = 0;
    for (int i = lo; i < hi; i++) s += cnt[i];
    part[t] = s;
    __syncthreads();
    for (int d = 1; d < 1024; d <<= 1) {
        int v = (t >= d) ? part[t - d] : 0;
        __syncthreads();
        part[t] += v;
        __syncthreads();
    }
    int base = (t == 0) ? 0 : part[t - 1];
    for (int i = lo; i < hi; i++) {
        off[i] = base;
        cursor[i] = base;
        base += cnt[i];
    }
    if (t == 0) off[NN] = EE;
}

// ---- counting sort, phase 3: scatter edges into receiver-sorted order ----
__global__ void scatter_kernel(const int* __restrict__ ei, int* __restrict__ cursor,
                               int2* __restrict__ ssr) {
    int e = blockIdx.x * 256 + threadIdx.x;
    int s = ei[e], r = ei[EE + e];
    int pos = atomicAdd(&cursor[r], 1);
    ssr[pos] = make_int2(s, r);
}

// ---- prep: pack 6 128x128 weight blocks into MFMA B-fragment order + w1c ----
__global__ void pack_w_kernel(const float* __restrict__ W1, const float* __restrict__ W2,
                              const float* __restrict__ U1, const float* __restrict__ U2,
                              unsigned short* __restrict__ packs,
                              float* __restrict__ w1c_out) {
    int t = blockIdx.x * blockDim.x + threadIdx.x;   // 385 blocks: 6*16384 pack + 128 w1c
    if (t >= 98304) {
        int d = t - 98304;
        if (d < 128) w1c_out[d] = W1[d * 257 + 256];
        return;
    }
    int mat = t >> 14;
    int r = t & 16383;
    int j = r & 7;
    int lane = (r >> 3) & 63;
    int f = r >> 9;            // 0..31
    int ks = f & 3, nt = f >> 2;
    int n = nt * 16 + (lane & 15);
    int k = ks * 32 + (lane >> 4) * 8 + j;
    float v;
    switch (mat) {
        case 0: v = W1[n * 257 + k];        break;  // W1a (vs h_sender)
        case 1: v = W1[n * 257 + 128 + k];  break;  // W1b (vs h_receiver)
        case 2: v = W2[n * 128 + k];        break;  // W2
        case 3: v = U1[n * 256 + k];        break;  // U1a (vs h)
        case 4: v = U1[n * 256 + 128 + k];  break;  // U1b (vs agg)
        default: v = U2[n * 128 + k];       break;  // U2
    }
    packs[t] = (unsigned short)f2bf(v);
}

// ---- prep_g: per-node G1a = h*W1a^T + b1, G1b = h*W1b^T, stored bf16 [NN][256] ----
__global__ __launch_bounds__(256, 2) void prep_g_kernel(
    const unsigned short* __restrict__ hp,
    const bf16x8* __restrict__ w1a_pack,
    const bf16x8* __restrict__ w1b_pack,
    const float* __restrict__ b1,
    unsigned short* __restrict__ G)
{
    const int tid = threadIdx.x;
    const int wave = tid >> 6, lane = tid & 63;
    const int quad = lane >> 4, l15 = lane & 15;
    const int nbase = blockIdx.x * 64 + wave * 16;

    int n = nbase + l15;
    int nrow = n < NN ? n : NN - 1;

    bf16x8 ah[4];
    #pragma unroll
    for (int ks = 0; ks < 4; ks++)
        ah[ks] = *(const bf16x8*)(hp + (size_t)nrow * DD + ks * 32 + quad * 8);

    f32x4 acca[8], accb[8];
    #pragma unroll
    for (int nt = 0; nt < 8; nt++) {
        acca[nt] = f32x4{0.f, 0.f, 0.f, 0.f};
        accb[nt] = f32x4{0.f, 0.f, 0.f, 0.f};
    }

    #pragma unroll
    for (int ks = 0; ks < 4; ks++) {
        #pragma unroll
        for (int nt = 0; nt < 8; nt++)
            acca[nt] = __builtin_amdgcn_mfma_f32_16x16x32_bf16(
                ah[ks], w1a_pack[(nt * 4 + ks) * 64 + lane], acca[nt], 0, 0, 0);
        #pragma unroll
        for (int nt = 0; nt < 8; nt++)
            accb[nt] = __builtin_amdgcn_mfma_f32_16x16x32_bf16(
                ah[ks], w1b_pack[(nt * 4 + ks) * 64 + lane], accb[nt], 0, 0, 0);
    }

    #pragma unroll
    for (int nt = 0; nt < 8; nt++) {
        int d = nt * 16 + l15;
        float b1v = b1[d];
        #pragma unroll
        for (int r = 0; r < 4; r++) {
            int n2 = nbase + quad * 4 + r;
            if (n2 < NN) {
                G[(size_t)n2 * 256 + d]       = (unsigned short)f2bf(acca[nt][r] + b1v);
                G[(size_t)n2 * 256 + 128 + d] = (unsigned short)f2bf(accb[nt][r]);
            }
        }
    }
}

// ---- edge kernel (receiver-sorted): gather G -> silu -> W2 MFMA ->
//      in-register segmented reduction, fp32 atomics only at segment boundaries ----
__global__ __launch_bounds__(256, 4) void edge_kernel(
    const unsigned short* __restrict__ G,      // [NN][256] bf16: [G1a+b1 | G1b]
    const float* __restrict__ coords,          // [NN][3]
    const int2* __restrict__ ssr,              // [EE] (send, recv), sorted by recv
    const bf16x8* __restrict__ w2_pack,        // 32 KB
    const float* __restrict__ w1c,             // [128] fp32, k-order
    const float* __restrict__ b2,
    float* __restrict__ agg)                   // [NN][128] fp32
{
    __shared__ int send_s[4][64];
    __shared__ int recv_s[4][64];
    __shared__ float dist_s[4][64];
    __shared__ float msm[4][16][132];          // per-wave message tile, +4 pad

    const int tid = threadIdx.x;
    const int wave = tid >> 6, lane = tid & 63;
    const int quad = lane >> 4, l15 = lane & 15;
    const int ebase = blockIdx.x * 256 + wave * 64;

    {
        int2 sr = ssr[ebase + lane];
        send_s[wave][lane] = sr.x;
        recv_s[wave][lane] = sr.y;
        float dx = coords[3 * sr.x + 0] - coords[3 * sr.y + 0];
        float dy = coords[3 * sr.x + 1] - coords[3 * sr.y + 1];
        float dz = coords[3 * sr.x + 2] - coords[3 * sr.y + 2];
        dist_s[wave][lane] = sqrtf(dx * dx + dy * dy + dz * dz);
    }
    __syncthreads();

    // per-lane constants: w1c at k = ks*32 + quad*8 + j (this lane's A-frag k-range)
    float w1cf[4][8];
    #pragma unroll
    for (int ks = 0; ks < 4; ks++) {
        f32x4 c0 = *(const f32x4*)(w1c + ks * 32 + quad * 8);
        f32x4 c1 = *(const f32x4*)(w1c + ks * 32 + quad * 8 + 4);
        #pragma unroll
        for (int j = 0; j < 4; j++) { w1cf[ks][j] = c0[j]; w1cf[ks][4 + j] = c1[j]; }
    }
    float b2f[8];
    #pragma unroll
    for (int nt = 0; nt < 8; nt++) b2f[nt] = b2[nt * 16 + l15];

    // tile-0 gathers (plain loads: G is 25.6MB, let L2/L3 keep it;
    // receiver rows are near-uniform within a tile after the sort)
    bf16x8 ga[4], gb[4];
    {
        int sr = send_s[wave][l15], rr = recv_s[wave][l15];
        #pragma unroll
        for (int ks = 0; ks < 4; ks++) {
            ga[ks] = *(const bf16x8*)(G + (size_t)sr * 256 + ks * 32 + quad * 8);
            gb[ks] = *(const bf16x8*)(G + (size_t)rr * 256 + 128 + ks * 32 + quad * 8);
        }
    }

    // segmented-reduction state: each lane owns 2 columns of agg
    float acc0 = 0.f, acc1 = 0.f;
    int cur = recv_s[wave][0];
    const int c0 = lane << 1;

    #pragma unroll
    for (int mt = 0; mt < 4; mt++) {
        float dist = dist_s[wave][mt * 16 + l15];   // lane l15 = edge row in A-layout

        // layer-1 epilogue in registers, directly in A-fragment layout
        bf16x8 m1f[4];
        #pragma unroll
        for (int ks = 0; ks < 4; ks++) {
            #pragma unroll
            for (int j = 0; j < 8; j++) {
                float pre = bf2f(ga[ks][j]) + bf2f(gb[ks][j]) + dist * w1cf[ks][j];
                m1f[ks][j] = f2bf(fast_silu(pre));
            }
        }

        // prefetch next tile's gathers early
        if (mt < 3) {
            int sr2 = send_s[wave][(mt + 1) * 16 + l15];
            int rr2 = recv_s[wave][(mt + 1) * 16 + l15];
            #pragma unroll
            for (int ks = 0; ks < 4; ks++) {
                ga[ks] = *(const bf16x8*)(G + (size_t)sr2 * 256 + ks * 32 + quad * 8);
                gb[ks] = *(const bf16x8*)(G + (size_t)rr2 * 256 + 128 + ks * 32 + quad * 8);
            }
        }

        // layer 2: acc2 = M1 * W2^T
        f32x4 acc2[8];
        #pragma unroll
        for (int nt = 0; nt < 8; nt++) acc2[nt] = f32x4{0.f, 0.f, 0.f, 0.f};
        #pragma unroll
        for (int ks = 0; ks < 4; ks++)
            #pragma unroll
            for (int nt = 0; nt < 8; nt++)
                acc2[nt] = __builtin_amdgcn_mfma_f32_16x16x32_bf16(
                    m1f[ks], w2_pack[(nt * 4 + ks) * 64 + lane], acc2[nt], 0, 0, 0);

        // epilogue 2: silu(acc2 + b2) -> per-wave LDS tile [16 edges][128 dims]
        #pragma unroll
        for (int nt = 0; nt < 8; nt++) {
            #pragma unroll
            for (int r = 0; r < 4; r++) {
                msm[wave][quad * 4 + r][nt * 16 + l15] =
                    fast_silu(acc2[nt][r] + b2f[nt]);
            }
        }
        asm volatile("s_waitcnt lgkmcnt(0)" ::: "memory");

        // segmented accumulate over the 16 receiver-sorted rows.
        // recv_s reads are wave-uniform -> flush branch is uniform (no divergence).
        #pragma unroll
        for (int i = 0; i < 16; i++) {
            int ri = recv_s[wave][mt * 16 + i];
            if (ri != cur) {
                unsafeAtomicAdd(&agg[(size_t)cur * DD + c0], acc0);
                unsafeAtomicAdd(&agg[(size_t)cur * DD + c0 + 1], acc1);
                acc0 = 0.f; acc1 = 0.f;
                cur = ri;
            }
            float2 mv = *(const float2*)&msm[wave][i][c0];
            acc0 += mv.x;
            acc1 += mv.y;
        }
    }
    // final flush
    unsafeAtomicAdd(&agg[(size_t)cur * DD + c0], acc0);
    unsafeAtomicAdd(&agg[(size_t)cur * DD + c0 + 1], acc1);
}

// ---- node kernel: out = h + U2*silu(U1a*h + U1b*agg + c1) + c2 ----
__global__ __launch_bounds__(256, 4) void node_kernel(
    const unsigned short* __restrict__ hp,
    const float* __restrict__ hf,
    const float* __restrict__ agg,
    const bf16x8* __restrict__ u1a_pack,
    const bf16x8* __restrict__ u1b_pack,
    const bf16x8* __restrict__ u2_pack,
    const float* __restrict__ c1,
    const float* __restrict__ c2,
    float* __restrict__ out)
{
    __shared__ unsigned short u1s[4][16][136];

    const int tid = threadIdx.x;
    const int wave = tid >> 6, lane = tid & 63;
    const int quad = lane >> 4, l15 = lane & 15;
    const int nbase = blockIdx.x * 64 + wave * 16;

    int n = nbase + l15;
    int nrow = n < NN ? n : NN - 1;

    float c1v[8];
    #pragma unroll
    for (int nt = 0; nt < 8; nt++) c1v[nt] = c1[nt * 16 + l15];

    bf16x8 ah[4], ag[4];
    #pragma unroll
    for (int ks = 0; ks < 4; ks++) {
        ah[ks] = *(const bf16x8*)(hp + (size_t)nrow * DD + ks * 32 + quad * 8);
        const float* ap = agg + (size_t)nrow * DD + ks * 32 + quad * 8;
        f32x4 g0 = *(const f32x4*)ap;
        f32x4 g1 = *(const f32x4*)(ap + 4);
        bf16x8 t;
        t[0] = f2bf(g0[0]); t[1] = f2bf(g0[1]); t[2] = f2bf(g0[2]); t[3] = f2bf(g0[3]);
        t[4] = f2bf(g1[0]); t[5] = f2bf(g1[1]); t[6] = f2bf(g1[2]); t[7] = f2bf(g1[3]);
        ag[ks] = t;
    }

    f32x4 acc[8];
    #pragma unroll
    for (int nt = 0; nt < 8; nt++) acc[nt] = f32x4{0.f, 0.f, 0.f, 0.f};

    #pragma unroll
    for (int ks = 0; ks < 4; ks++) {
        #pragma unroll
        for (int nt = 0; nt < 8; nt++)
            acc[nt] = __builtin_amdgcn_mfma_f32_16x16x32_bf16(
                ah[ks], u1a_pack[(nt * 4 + ks) * 64 + lane], acc[nt], 0, 0, 0);
        #pragma unroll
        for (int nt = 0; nt < 8; nt++)
            acc[nt] = __builtin_amdgcn_mfma_f32_16x16x32_bf16(
                ag[ks], u1b_pack[(nt * 4 + ks) * 64 + lane], acc[nt], 0, 0, 0);
    }

    #pragma unroll
    for (int nt = 0; nt < 8; nt++) {
        int d = nt * 16 + l15;
        #pragma unroll
        for (int r = 0; r < 4; r++) {
            float pre = acc[nt][r] + c1v[nt];
            u1s[wave][quad * 4 + r][d] = (unsigned short)f2bf(fast_silu(pre));
        }
    }
    asm volatile("s_waitcnt lgkmcnt(0)" ::: "memory");

    bf16x8 a2[4];
    #pragma unroll
    for (int ks = 0; ks < 4; ks++)
        a2[ks] = *(const bf16x8*)(&u1s[wave][l15][ks * 32 + quad * 8]);

    f32x4 acc2[8];
    #pragma unroll
    for (int nt = 0; nt < 8; nt++) acc2[nt] = f32x4{0.f, 0.f, 0.f, 0.f};

    #pragma unroll
    for (int ks = 0; ks < 4; ks++)
        #pragma unroll
        for (int nt = 0; nt < 8; nt++)
            acc2[nt] = __builtin_amdgcn_mfma_f32_16x16x32_bf16(
                a2[ks], u2_pack[(nt * 4 + ks) * 64 + lane], acc2[nt], 0, 0, 0);

    #pragma unroll
    for (int nt = 0; nt < 8; nt++) {
        int d = nt * 16 + l15;
        float c2v = c2[d];
        #pragma unroll
        for (int r = 0; r < 4; r++) {
            int n2 = nbase + quad * 4 + r;
            if (n2 < NN) {
                size_t idx = (size_t)n2 * DD + d;
                out[idx] = hf[idx] + acc2[nt][r] + c2v;
            }
        }
    }
}

extern "C" void kernel_launch(void* const* d_in, const int* in_sizes, int n_in,
                              void* d_out, int out_size, void* d_ws, size_t ws_size,
                              hipStream_t stream) {
    const float* h      = (const float*)d_in[0];
    const float* coords = (const float*)d_in[1];
    const int* ei       = (const int*)d_in[2];   // int64 in reference -> int32 from harness
    const float* W1 = (const float*)d_in[3];
    const float* b1 = (const float*)d_in[4];
    const float* W2 = (const float*)d_in[5];
    const float* b2 = (const float*)d_in[6];
    const float* U1 = (const float*)d_in[7];
    const float* c1 = (const float*)d_in[8];
    const float* U2 = (const float*)d_in[9];
    const float* c2 = (const float*)d_in[10];
    float* out = (float*)d_out;

    char* ws = (char*)d_ws;
    float* agg = (float*)ws;                                    // 25,600,000 B fp32 [NN][128]
    unsigned short* hp = (unsigned short*)(ws + 25600000);      // 12,800,000 B bf16 h
    unsigned short* packs = (unsigned short*)(ws + 38400000);   // 196,608 B packed weights
    float* w1c = (float*)(ws + 38600000);                       // 512 B
    unsigned short* G = (unsigned short*)(ws + 38700000);       // 25,600,000 B bf16 [NN][256]
    int* cnt    = (int*)(ws + 64300000);                        // 200,000 B
    int* off    = (int*)(ws + 64500000);                        // 200,004 B
    int* cursor = (int*)(ws + 64700004);                        // 200,000 B
    int2* ssr   = (int2*)(ws + 64900008);                       // 6,400,000 B sorted (s,r)
    const bf16x8* w1a = (const bf16x8*)(packs);
    const bf16x8* w1b = (const bf16x8*)(packs + 16384);
    const bf16x8* w2p = (const bf16x8*)(packs + 32768);
    const bf16x8* u1a = (const bf16x8*)(packs + 49152);
    const bf16x8* u1b = (const bf16x8*)(packs + 65536);
    const bf16x8* u2p = (const bf16x8*)(packs + 81920);

    prep_kernel<<<6250, 256, 0, stream>>>(h, hp, (float4*)agg, cnt);
    pack_w_kernel<<<385, 256, 0, stream>>>(W1, W2, U1, U2, packs, w1c);
    hist_kernel<<<EE / 256, 256, 0, stream>>>(ei, cnt);
    scan_kernel<<<1, 1024, 0, stream>>>(cnt, off, cursor);
    scatter_kernel<<<EE / 256, 256, 0, stream>>>(ei, cursor, ssr);
    prep_g_kernel<<<(NN + 63) / 64, 256, 0, stream>>>(hp, w1a, w1b, b1, G);
    edge_kernel<<<EE / 256, 256, 0, stream>>>(G, coords, ssr, w2p, w1c, b2, agg);
    node_kernel<<<(NN + 63) / 64, 256, 0, stream>>>(hp, h, agg, u1a, u1b, u2p, c1, c2, out);
}